// Round 1
// 59.692 us; speedup vs baseline: 1.0298x; 1.0298x over previous
//
#include <hip/hip_runtime.h>

// StereoMatching: out[b,h,w] = left[b,h,w] * sum_{d=0..191, d<=w} d * right[b,h,w-d]
// B=2, C=1, H=384, W=1248, DISP=192.
//
// Full-row scan formulation (global index j within the row):
//   P[i] = sum_{j<i} right[j]          (exclusive prefix)
//   Q[i] = sum_{j<i} j*right[j]        (exclusive prefix)
//   S(w) = sum_{j=lo}^{w} (w-j)*right[j],  lo = max(0, w-191)
//        = w*(P[w+1]-P[lo]) - (Q[w+1]-Q[lo])
// One block per row: no halo re-reads, all global accesses aligned float4.

#define WID   1248
#define DISP  192
#define THREADS 320          // 5 waves; 320*4 = 1280 >= 1248
#define NROWS 768            // B*H

// Skewed LDS index: stride-4 access patterns rotate across all 32 banks.
#define SKEW(i) ((i) + ((i) >> 5))

__global__ __launch_bounds__(THREADS) void stereo_row_kernel(
    const float* __restrict__ left,
    const float* __restrict__ right,
    float* __restrict__ out)
{
    // Exclusive prefixes over the whole row. Max written index:
    // SKEW(1279) = 1318, so 1320 covers everything (padding threads write
    // harmless copies of the row total past index 1248).
    __shared__ float Ps[1320];
    __shared__ float Qs[1320];
    __shared__ float wsS[5], wsQ[5];

    const int  row  = blockIdx.x;
    const long base = (long)row * WID;
    const int  tid  = threadIdx.x;
    const int  lane = tid & 63;
    const int  wv   = tid >> 6;
    const int  i0   = tid << 2;          // first row element owned by this thread
    const bool active = (i0 < WID);

    // Aligned float4 loads (row base = 4992 B * row, 16B-aligned).
    // left is prefetched here so its latency hides under the scan.
    float e0 = 0.f, e1 = 0.f, e2 = 0.f, e3 = 0.f;
    float l0 = 0.f, l1 = 0.f, l2 = 0.f, l3 = 0.f;
    if (active) {
        const float4 ev = *reinterpret_cast<const float4*>(right + base + i0);
        const float4 lv = *reinterpret_cast<const float4*>(left  + base + i0);
        e0 = ev.x; e1 = ev.y; e2 = ev.z; e3 = ev.w;
        l0 = lv.x; l1 = lv.y; l2 = lv.z; l3 = lv.w;
    }

    const float fi0 = (float)i0;
    const float ts  = (e0 + e1) + (e2 + e3);
    const float tq  = fmaf(fi0,        e0,
                      fmaf(fi0 + 1.f,  e1,
                      fmaf(fi0 + 2.f,  e2, (fi0 + 3.f) * e3)));

    // Inclusive 64-lane wave scan of the per-thread (sum, weighted-sum) pair.
    float s = ts, q = tq;
    #pragma unroll
    for (int d = 1; d < 64; d <<= 1) {
        const float us = __shfl_up(s, (unsigned)d, 64);
        const float uq = __shfl_up(q, (unsigned)d, 64);
        if (lane >= d) { s += us; q += uq; }
    }
    if (lane == 63) { wsS[wv] = s; wsQ[wv] = q; }
    __syncthreads();

    float offS = 0.f, offQ = 0.f;
    #pragma unroll
    for (int w2 = 0; w2 < 4; ++w2) {
        if (wv > w2) { offS += wsS[w2]; offQ += wsQ[w2]; }
    }

    // Exclusive prefix before element i0, then walk the 4 owned elements.
    float p  = offS + (s - ts);
    float qv = offQ + (q - tq);

    Ps[SKEW(i0)]     = p;   Qs[SKEW(i0)]     = qv;
    p += e0;                qv = fmaf(fi0,       e0, qv);
    Ps[SKEW(i0 + 1)] = p;   Qs[SKEW(i0 + 1)] = qv;
    p += e1;                qv = fmaf(fi0 + 1.f, e1, qv);
    Ps[SKEW(i0 + 2)] = p;   Qs[SKEW(i0 + 2)] = qv;
    p += e2;                qv = fmaf(fi0 + 2.f, e2, qv);
    Ps[SKEW(i0 + 3)] = p;   Qs[SKEW(i0 + 3)] = qv;
    // P[1248] (row total) is written by thread 312 (i0 == 1248) as its base entry.
    __syncthreads();

    if (active) {
        float r0, r1, r2, r3;
        {
            const int w  = i0;
            const int lo = (w > DISP - 1) ? (w - (DISP - 1)) : 0;
            const float A  = Ps[SKEW(w + 1)] - Ps[SKEW(lo)];
            const float Qw = Qs[SKEW(w + 1)] - Qs[SKEW(lo)];
            r0 = l0 * fmaf((float)w, A, -Qw);
        }
        {
            const int w  = i0 + 1;
            const int lo = (w > DISP - 1) ? (w - (DISP - 1)) : 0;
            const float A  = Ps[SKEW(w + 1)] - Ps[SKEW(lo)];
            const float Qw = Qs[SKEW(w + 1)] - Qs[SKEW(lo)];
            r1 = l1 * fmaf((float)w, A, -Qw);
        }
        {
            const int w  = i0 + 2;
            const int lo = (w > DISP - 1) ? (w - (DISP - 1)) : 0;
            const float A  = Ps[SKEW(w + 1)] - Ps[SKEW(lo)];
            const float Qw = Qs[SKEW(w + 1)] - Qs[SKEW(lo)];
            r2 = l2 * fmaf((float)w, A, -Qw);
        }
        {
            const int w  = i0 + 3;
            const int lo = (w > DISP - 1) ? (w - (DISP - 1)) : 0;
            const float A  = Ps[SKEW(w + 1)] - Ps[SKEW(lo)];
            const float Qw = Qs[SKEW(w + 1)] - Qs[SKEW(lo)];
            r3 = l3 * fmaf((float)w, A, -Qw);
        }
        *reinterpret_cast<float4*>(out + base + i0) = make_float4(r0, r1, r2, r3);
    }
}

extern "C" void kernel_launch(void* const* d_in, const int* in_sizes, int n_in,
                              void* d_out, int out_size, void* d_ws, size_t ws_size,
                              hipStream_t stream) {
    const float* left  = (const float*)d_in[0];
    const float* right = (const float*)d_in[1];
    float* out = (float*)d_out;
    stereo_row_kernel<<<dim3(NROWS), dim3(THREADS), 0, stream>>>(left, right, out);
}